// Round 2
// baseline (218.777 us; speedup 1.0000x reference)
//
#include <hip/hip_runtime.h>
#include <stdint.h>

// Problem: x (32,128,8192) f32, weight (128,128,1,2) f32
// out[b,o,p] = sum_{c,k} x[b,c,2p+k] * w[o,c,k] / sqrt(128),  out (32,128,4096) f32
// GEMM: M=(b,p)=131072, N=o=128, K=(c,k)=256. Memory-bound with bf16 MFMA.
//
// R4: R3 (single kernel, B staged in LDS so the in-order vmcnt queue carries
// ONLY the distance-1 A prefetch) with the prologue bank conflict fixed:
//   - store mapping transposed: kgrp = t&31 varies fastest in the wave, o in
//     the slow bits -> global weight reads stay coalesced (1 KB / 32 lanes)
//   - LDS layout XOR-swizzled: dword idx = kgrp*512 + (o ^ (kgrp&7))*4 + kpair.
//     XOR touches only bits 0-2 of the o field, so b128 units stay contiguous;
//     both ds_write_b128 (prologue) and ds_read_b128 (main loop) have every
//     consecutive-8-lane group covering all 32 banks -> conflict-free.
// R3's prologue was a 32-way write conflict (~4.5 us/CU of LDS serialization).

typedef __attribute__((ext_vector_type(8))) short bf16x8;   // 8 bf16 = 4 VGPRs
typedef __attribute__((ext_vector_type(4))) float f32x4;    // MFMA C/D

#define CIN  128
#define DLEN 8192
#define PLEN 4096
#define COUT 128

// pack two fp32 -> bf16x2 (RTNE), lo = a, hi = b
__device__ inline unsigned pack_bf(float a, float b) {
    unsigned ua = __builtin_bit_cast(unsigned, a);
    unsigned ub = __builtin_bit_cast(unsigned, b);
    unsigned ra = ua + 0x7FFFu + ((ua >> 16) & 1u);
    unsigned rb = ub + 0x7FFFu + ((ub >> 16) & 1u);
    return (ra >> 16) | (rb & 0xFFFF0000u);
}

// One block = 8 waves = 512 threads, covers 256 positions of one batch, all
// 128 outputs, K=256. Each wave: 32 consecutive positions, interleaved across
// two 16x16 M-tiles (tile0 = even offsets, tile1 = odd), so each A row load is
// one float4 covering both tiles. B (weights) staged once per block into LDS
// in swizzled fragment-major bf16 layout (see header comment).
__global__ __launch_bounds__(512, 4) void conv_mfma(const float* __restrict__ x,
                                                    const float* __restrict__ wsrc,
                                                    float* __restrict__ out) {
    __shared__ unsigned wlds[16384];   // 64 KB

    // ---- prologue: convert weights f32 -> bf16 into LDS, scale folded ----
    {
        const float scale = 0.088388347648318447f; // 1/sqrt(128)
        int kgrp  = threadIdx.x & 31;              // kk group (kk>>3), fast in wave
        int obase = threadIdx.x >> 5;              // 0..15
        unsigned swz = (unsigned)(kgrp & 7);
        const float* wp0 = wsrc + kgrp * 8;
#pragma unroll
        for (int i = 0; i < 8; ++i) {
            int o = obase + 16 * i;                // 0..127
            const float* wp = wp0 + o * 256;
            float4 f0 = *(const float4*)(wp);
            float4 f1 = *(const float4*)(wp + 4);
            uint4 v;
            v.x = pack_bf(f0.x * scale, f0.y * scale);
            v.y = pack_bf(f0.z * scale, f0.w * scale);
            v.z = pack_bf(f1.x * scale, f1.y * scale);
            v.w = pack_bf(f1.z * scale, f1.w * scale);
            *(uint4*)&wlds[kgrp * 512 + ((unsigned)o ^ swz) * 4] = v;
        }
    }
    __syncthreads();

    int tile = blockIdx.x;            // 0..511
    int b    = tile >> 4;             // 0..31
    int pt   = (tile & 15) * 256;     // position base of block
    int lane = threadIdx.x & 63;
    int w    = threadIdx.x >> 6;      // wave 0..7
    int quad = lane >> 4;
    int l16  = lane & 15;
    int pbase = pt + w * 32;          // wave's 32-position strip

    // A lane base: row c = quad*4 (+jj, +16*kc), elem 2*pbase + 4*l16
    const float* xl = x + (size_t)b * ((size_t)CIN * DLEN)
                        + (size_t)(quad * 4) * DLEN + 2 * pbase + 4 * l16;
    // B bases: kgrp = kc*4+quad -> swizzle value (kgrp&7) = quad + 4*(kc&1).
    // o = l16 + 16*f; XOR only affects l16's bits. Two bases, picked by kc&1.
    const unsigned* bb0 = wlds + quad * 512 + (unsigned)(l16 ^ quad) * 4;
    const unsigned* bb1 = wlds + quad * 512 + (unsigned)(l16 ^ quad ^ 4) * 4;

    f32x4 acc[2][8];
#pragma unroll
    for (int mt = 0; mt < 2; ++mt)
#pragma unroll
        for (int t = 0; t < 8; ++t)
            acc[mt][t] = (f32x4)(0.0f);

    // preload kc=0 A
    float4 abuf[4];
#pragma unroll
    for (int jj = 0; jj < 4; ++jj)
        abuf[jj] = *(const float4*)(xl + (size_t)jj * DLEN);

#pragma unroll 1
    for (int kc = 0; kc < 8; ++kc) {
        // consume current A: .x/.y -> tile0 (even pos), .z/.w -> tile1 (odd pos)
        union { bf16x8 v; unsigned uu[4]; } afr0, afr1;
#pragma unroll
        for (int jj = 0; jj < 4; ++jj) {
            afr0.uu[jj] = pack_bf(abuf[jj].x, abuf[jj].y);
            afr1.uu[jj] = pack_bf(abuf[jj].z, abuf[jj].w);
        }
        // prefetch next kc A (distance 1, same regs — abuf already consumed)
        if (kc < 7) {
            const float* nx = xl + (size_t)((kc + 1) * 16) * DLEN;
#pragma unroll
            for (int jj = 0; jj < 4; ++jj)
                abuf[jj] = *(const float4*)(nx + (size_t)jj * DLEN);
        }
        // B fragments for this kc from LDS (lgkm path, vmcnt untouched)
        const unsigned* bk = ((kc & 1) ? bb1 : bb0) + kc * 2048;
#pragma unroll
        for (int th = 0; th < 2; ++th) {
            union { bf16x8 v; uint4 u; } bfr[4];
#pragma unroll
            for (int tt = 0; tt < 4; ++tt)
                bfr[tt].u = *(const uint4*)(bk + (th * 4 + tt) * 64);
#pragma unroll
            for (int tt = 0; tt < 4; ++tt) {
                int t = th * 4 + tt;
                acc[0][t] = __builtin_amdgcn_mfma_f32_16x16x32_bf16(afr0.v, bfr[tt].v, acc[0][t], 0, 0, 0);
                acc[1][t] = __builtin_amdgcn_mfma_f32_16x16x32_bf16(afr1.v, bfr[tt].v, acc[1][t], 0, 0, 0);
            }
        }
    }

    // Epilogue: C/D row = quad*4 + reg. tile0 reg r -> p = pbase+8q+2r,
    // tile1 -> +1. Interleave regs -> 8 consecutive positions per t.
    float* ob = out + (size_t)b * ((size_t)COUT * PLEN) + pbase + quad * 8;
#pragma unroll
    for (int t = 0; t < 8; ++t) {
        int o = t * 16 + l16;
        float* orow = ob + (size_t)o * PLEN;
        f32x4 v0 = { acc[0][t][0], acc[1][t][0], acc[0][t][1], acc[1][t][1] };
        f32x4 v1 = { acc[0][t][2], acc[1][t][2], acc[0][t][3], acc[1][t][3] };
        *(f32x4*)(orow)     = v0;
        *(f32x4*)(orow + 4) = v1;
    }
}

extern "C" void kernel_launch(void* const* d_in, const int* in_sizes, int n_in,
                              void* d_out, int out_size, void* d_ws, size_t ws_size,
                              hipStream_t stream) {
    const float* x = (const float*)d_in[0];
    const float* w = (const float*)d_in[1];
    float* out = (float*)d_out;
    (void)d_ws; (void)ws_size;

    conv_mfma<<<512, 512, 0, stream>>>(x, w, out);
}